// Round 1
// baseline (3092.492 us; speedup 1.0000x reference)
//
#include <hip/hip_runtime.h>
#include <math.h>

#define NB 16
#define NCH 16
#define NL 13
#define NN 1024
#define NT 12
#define CLR 208      // NCH*NL rows of the graph-conv GEMM
#define NLAY 8

// workspace layout (float offsets)
#define OFF_TAB   0                                   // 384 floats of tables
#define OFF_SRC   1024
#define OFF_TEMP  (OFF_SRC + NB*NN*32)
#define OFF_A     (OFF_TEMP + NB*NN*32)
#define OFF_X     (OFF_A + (size_t)NB*NN*NN)
#define OFF_XS    (OFF_X + (size_t)NB*NCH*NL*NN)
#define OFF_H1    (OFF_XS + (size_t)NB*NCH*NL*NN)
#define OFF_H2    (OFF_H1 + (size_t)NB*NCH*NL*NN)
#define OFF_SKIP  (OFF_H2 + (size_t)NB*NCH*NL*NN)
#define WS_FLOATS (OFF_SKIP + (size_t)NB*832*NN)

// ---------------- tables: bn scale + x_a affine recurrence ----------------
// tab[0..127]   = bnscale[i][c]  = bn_g[i][c]/sqrt(1+eps)
// tab[128..255] = Acoef[i][c]    (x_a_i = Acoef*u1 + Bcoef, u1 = raw input ch1)
// tab[256..383] = Bcoef[i][c]
__global__ void k_tables(const float* __restrict__ bn_g,
                         const float* __restrict__ bna_g, const float* __restrict__ bna_b,
                         const float* __restrict__ sa_w, const float* __restrict__ sa_b,
                         float* __restrict__ tab) {
    int c = threadIdx.x;
    if (c >= 16) return;
    float inv = 1.0f / sqrtf(1.0f + 1e-5f);
    float A = sa_w[c], Bc = sa_b[c];
    for (int i = 0; i < NLAY; i++) {
        tab[i*16 + c]       = bn_g[i*16 + c] * inv;
        tab[128 + i*16 + c] = A;
        tab[256 + i*16 + c] = Bc;
        float ga = bna_g[i*16 + c] * inv;
        A  = 2.0f * ga * A;
        Bc = 2.0f * ga * Bc + bna_b[i*16 + c];
    }
}

// ---------------- start conv: x0[b,c,l,n] = sw[c]*u0 + sb[c] ----------------
__global__ __launch_bounds__(256) void k_start(const float* __restrict__ inp,
                        const float* __restrict__ sw, const float* __restrict__ sb,
                        float* __restrict__ x) {
    int idx = blockIdx.x * 256 + threadIdx.x;            // over B*C*L*N
    int n = idx & 1023;
    int rest = idx >> 10;
    int l = rest % 13; rest /= 13;
    int c = rest & 15;
    int b = rest >> 4;
    float u = (l == 0) ? 0.f : inp[((size_t)(b*2 + 0)*NN + n)*NT + (l - 1)];
    x[idx] = sw[c] * u + sb[c];
}

// ---------------- adp / src / temp (one block per batch) ----------------
__global__ __launch_bounds__(256) void k_srctemp(const float* __restrict__ p1, const int* __restrict__ ind,
                          const float* __restrict__ pk, const float* __restrict__ p2,
                          const float* __restrict__ p3,
                          float* __restrict__ src, float* __restrict__ temp) {
    __shared__ float te[32];
    __shared__ float adp[32][32];
    __shared__ float M[32][32];
    __shared__ float p3s[32][32];
    int b = blockIdx.x, t = threadIdx.x;
    if (t < 32) te[t] = p1[(size_t)ind[b]*32 + t];
    for (int i = t; i < 1024; i += 256) p3s[i >> 5][i & 31] = p3[i];   // first 32 rows of p3
    __syncthreads();
    for (int i = t; i < 1024; i += 256) {                 // adp[j][k] = sum_i te[i]*pk[i,j,k]
        int j = i >> 5, k = i & 31;
        float s = 0.f;
        for (int q = 0; q < 32; q++) s += te[q] * pk[q*1024 + j*32 + k];
        adp[j][k] = s;
    }
    __syncthreads();
    for (int i = t; i < 1024; i += 256) {                 // M[j][c] = sum_k adp[j][k]*p3[c][k]
        int j = i >> 5, c = i & 31;
        float s = 0.f;
        for (int k = 0; k < 32; k++) s += adp[j][k] * p3s[c][k];
        M[j][c] = s;
    }
    __syncthreads();
    for (int n0 = 0; n0 < NN; n0 += 8) {                  // src = p2·adp ; temp = p2·M
        int n = n0 + (t >> 5), k = t & 31;
        float rs = 0.f, rt = 0.f;
        for (int j = 0; j < 32; j++) {
            float pv = p2[n*32 + j];
            rs += pv * adp[j][k];
            rt += pv * M[j][k];
        }
        src [((size_t)b*NN + n)*32 + k] = rs;
        temp[((size_t)b*NN + n)*32 + k] = rt;
    }
}

// ---------------- A[b,n,m] = relu(tanh(x1[n,m]-x1[m,n])) ----------------
__global__ __launch_bounds__(256) void k_A(const float* __restrict__ src, const float* __restrict__ temp,
                    float* __restrict__ Amat) {
    int b = blockIdx.z, n0 = blockIdx.y*64, m0 = blockIdx.x*64;
    __shared__ float sn[64][33], tm[64][33], sm[64][33], tn[64][33];
    int t = threadIdx.x;
    const float* sb_ = src  + (size_t)b*NN*32;
    const float* tb_ = temp + (size_t)b*NN*32;
    for (int i = t; i < 64*32; i += 256) {
        int r = i >> 5, k = i & 31;
        sn[r][k] = sb_[(n0 + r)*32 + k];
        tm[r][k] = tb_[(m0 + r)*32 + k];
        sm[r][k] = sb_[(m0 + r)*32 + k];
        tn[r][k] = tb_[(n0 + r)*32 + k];
    }
    __syncthreads();
    int tr = (t >> 4) * 4, tc = (t & 15) * 4;
    float acc1[4][4] = {}, acc2[4][4] = {};
    for (int k = 0; k < 32; k++) {
        float a[4], bb[4], c2[4], d2[4];
        #pragma unroll
        for (int i = 0; i < 4; i++) { a[i]=sn[tr+i][k]; bb[i]=tm[tc+i][k]; c2[i]=sm[tc+i][k]; d2[i]=tn[tr+i][k]; }
        #pragma unroll
        for (int i = 0; i < 4; i++)
            #pragma unroll
            for (int j = 0; j < 4; j++) { acc1[i][j] += a[i]*bb[j]; acc2[i][j] += c2[j]*d2[i]; }
    }
    for (int i = 0; i < 4; i++)
        for (int j = 0; j < 4; j++) {
            float v = tanhf(acc1[i][j] - acc2[i][j]);
            Amat[((size_t)b*NN + n0 + tr + i)*NN + m0 + tc + j] = v > 0.f ? v : 0.f;
        }
}

// ---------------- per-layer: fc1/relu/fc2/sigmoid + skip conv ----------------
__global__ __launch_bounds__(256) void k_fc(const float* __restrict__ x, float* __restrict__ xs,
                     float* __restrict__ skip, const float* __restrict__ fc1,
                     const float* __restrict__ fc2, const float* __restrict__ skw,
                     const float* __restrict__ skb, int layer) {
    __shared__ float W1[256], W2[256], W3[128], B3[8];
    int t = threadIdx.x;
    if (t < 256) { W1[t] = fc1[t]; W2[t] = fc2[t]; }
    if (t < 128) W3[t] = skw[layer*128 + t];
    if (t < 8)   B3[t] = skb[layer*8 + t];
    __syncthreads();
    int idx = blockIdx.x*256 + t;                         // over (b,l,n)
    int n = idx & 1023;
    int q = idx >> 10;
    int l = q % 13, b = q / 13;
    size_t base = ((size_t)b*NCH*NL + l)*NN + n;
    float v[16], t1[16], v2[16];
    #pragma unroll
    for (int c = 0; c < 16; c++) v[c] = x[base + (size_t)c*NL*NN];
    #pragma unroll
    for (int c = 0; c < 16; c++) {
        float s = 0.f;
        #pragma unroll
        for (int j = 0; j < 16; j++) s += W1[c*16 + j] * v[j];
        t1[c] = fmaxf(s, 0.f);
    }
    #pragma unroll
    for (int c = 0; c < 16; c++) {
        float s = 0.f;
        #pragma unroll
        for (int j = 0; j < 16; j++) s += W2[c*16 + j] * t1[j];
        float z = 2.f*s + v[c];
        v2[c] = 1.f / (1.f + expf(-z));
        xs[base + (size_t)c*NL*NN] = v2[c];
    }
    #pragma unroll
    for (int sc = 0; sc < 8; sc++) {
        float s = B3[sc];
        #pragma unroll
        for (int c = 0; c < 16; c++) s += W3[sc*16 + c] * v2[c];
        skip[((size_t)b*832 + (7 - layer)*104 + sc*13 + l)*NN + n] = s;
    }
}

// ---------------- C(208x1024) = X(208x1024) · A^T, per batch ----------------
__global__ __launch_bounds__(256) void k_gemm(const float* __restrict__ Xg, const float* __restrict__ Ag,
                       float* __restrict__ Cg) {
    __shared__ alignas(16) float Xs[32][68];
    __shared__ alignas(16) float As[32][68];
    int b = blockIdx.z;
    int n0 = blockIdx.x * 64, m0 = blockIdx.y * 64;
    const float* Xb = Xg + (size_t)b*CLR*NN;
    const float* Ab = Ag + (size_t)b*NN*NN;
    int t = threadIdx.x;
    int ty = t >> 4, tx = t & 15;
    float acc[4][4] = {};
    for (int k0 = 0; k0 < NN; k0 += 32) {
        for (int i = t; i < 2048; i += 256) {
            int m = i >> 5, k = i & 31;
            int gm = m0 + m;
            Xs[k][m] = (gm < CLR) ? Xb[(size_t)gm*NN + k0 + k] : 0.f;
            As[k][m] = Ab[(size_t)(n0 + m)*NN + k0 + k];
        }
        __syncthreads();
        #pragma unroll 8
        for (int k = 0; k < 32; k++) {
            float4 av = *(const float4*)&Xs[k][ty*4];
            float4 bv = *(const float4*)&As[k][tx*4];
            float a[4] = {av.x, av.y, av.z, av.w};
            float bb[4] = {bv.x, bv.y, bv.z, bv.w};
            #pragma unroll
            for (int i = 0; i < 4; i++)
                #pragma unroll
                for (int j = 0; j < 4; j++) acc[i][j] += a[i]*bb[j];
        }
        __syncthreads();
    }
    for (int i = 0; i < 4; i++) {
        int gm = m0 + ty*4 + i;
        if (gm < CLR)
            for (int j = 0; j < 4; j++)
                Cg[(size_t)b*CLR*NN + (size_t)gm*NN + n0 + tx*4 + j] = acc[i][j];
    }
}

// ---------------- per-layer epilogue: gconv + x_a + residual + bn ----------------
__global__ __launch_bounds__(256) void k_epi(float* __restrict__ x, const float* __restrict__ xs,
                      const float* __restrict__ h1, const float* __restrict__ h2,
                      const float* __restrict__ inp, const float* __restrict__ gw,
                      const float* __restrict__ gb, const float* __restrict__ bnb,
                      const float* __restrict__ tab, int layer) {
    __shared__ float W[768], GB[16], BNB[16], BNS[16], AC[16], BC[16];
    int t = threadIdx.x;
    for (int i = t; i < 768; i += 256) W[i] = gw[layer*768 + i];
    if (t < 16) {
        GB[t]  = gb[layer*16 + t];
        BNB[t] = bnb[layer*16 + t];
        BNS[t] = tab[layer*16 + t];
        AC[t]  = tab[128 + layer*16 + t];
        BC[t]  = tab[256 + layer*16 + t];
    }
    __syncthreads();
    int idx = blockIdx.x*256 + t;
    int n = idx & 1023;
    int q = idx >> 10;
    int l = q % 13, b = q / 13;
    float u1 = (l == 0) ? 0.f : inp[((size_t)(b*2 + 1)*NN + n)*NT + (l - 1)];
    size_t base = ((size_t)b*NCH*NL + l)*NN + n;
    float vx[16], v1[16], v2[16], vo[16];
    #pragma unroll
    for (int c = 0; c < 16; c++) {
        size_t o = base + (size_t)c*NL*NN;
        vx[c] = xs[o]; v1[c] = h1[o]; v2[c] = h2[o]; vo[c] = x[o];
    }
    #pragma unroll
    for (int o = 0; o < 16; o++) {
        float s = GB[o];
        #pragma unroll
        for (int c = 0; c < 16; c++) s += W[o*48 + c]      * vx[c];
        #pragma unroll
        for (int c = 0; c < 16; c++) s += W[o*48 + 16 + c] * v1[c];
        #pragma unroll
        for (int c = 0; c < 16; c++) s += W[o*48 + 32 + c] * v2[c];
        float xa = AC[o]*u1 + BC[o];
        x[base + (size_t)o*NL*NN] = BNS[o]*(s + xa + vo[o]) + BNB[o];
    }
}

// ---------------- end: out = end2·relu(end1·relu(skip)+b1)+b2 ----------------
__global__ __launch_bounds__(256) void k_end(const float* __restrict__ skip, const float* __restrict__ w1,
                      const float* __restrict__ b1, const float* __restrict__ w2,
                      const float* __restrict__ b2, float* __restrict__ outp) {
    __shared__ alignas(16) float Ss[64][68];
    __shared__ alignas(16) float Ws[64][68];
    int b = blockIdx.y, n0 = blockIdx.x * 64;
    int t = threadIdx.x, ty = t >> 4, tx = t & 15;
    float acc[4][4] = {};
    for (int k0 = 0; k0 < 832; k0 += 64) {
        for (int i = t; i < 4096; i += 256) {
            int r = i >> 6, c = i & 63;
            float sv = skip[((size_t)b*832 + k0 + r)*NN + n0 + c];
            Ss[r][c] = sv > 0.f ? sv : 0.f;                       // relu(skip)
            Ws[c][r] = w1[(size_t)r*832 + k0 + c];                // Ws[k][o]
        }
        __syncthreads();
        #pragma unroll 8
        for (int k = 0; k < 64; k++) {
            float4 av = *(const float4*)&Ws[k][ty*4];
            float4 bv = *(const float4*)&Ss[k][tx*4];
            float a[4] = {av.x, av.y, av.z, av.w};
            float bb[4] = {bv.x, bv.y, bv.z, bv.w};
            #pragma unroll
            for (int i = 0; i < 4; i++)
                #pragma unroll
                for (int j = 0; j < 4; j++) acc[i][j] += a[i]*bb[j];
        }
        __syncthreads();
    }
    // o1 = relu(acc + b1) staged to smem, then 12x64 final conv
    #pragma unroll
    for (int i = 0; i < 4; i++) {
        float bias = b1[ty*4 + i];
        #pragma unroll
        for (int j = 0; j < 4; j++) {
            float v = acc[i][j] + bias;
            Ss[ty*4 + i][tx*4 + j] = v > 0.f ? v : 0.f;
        }
    }
    __syncthreads();
    for (int idx = t; idx < 12*64; idx += 256) {
        int j = idx >> 6, n = idx & 63;
        float s = b2[j];
        for (int o = 0; o < 64; o++) s += w2[j*64 + o] * Ss[o][n];
        outp[((size_t)b*12 + j)*NN + n0 + n] = s;
    }
}

extern "C" void kernel_launch(void* const* d_in, const int* in_sizes, int n_in,
                              void* d_out, int out_size, void* d_ws, size_t ws_size,
                              hipStream_t stream) {
    (void)in_sizes; (void)n_in; (void)out_size;
    if (ws_size < WS_FLOATS * sizeof(float)) return;   // diagnostic: output stays zero

    const float* inputs  = (const float*)d_in[0];
    const int*   ind     = (const int*)  d_in[1];
    const float* start_w = (const float*)d_in[2];
    const float* start_b = (const float*)d_in[3];
    const float* starta_w= (const float*)d_in[4];
    const float* starta_b= (const float*)d_in[5];
    const float* p1      = (const float*)d_in[6];
    const float* p2      = (const float*)d_in[7];
    const float* p3      = (const float*)d_in[8];
    const float* pk      = (const float*)d_in[9];
    const float* fc1_w   = (const float*)d_in[10];
    const float* fc2_w   = (const float*)d_in[11];
    const float* skip_w  = (const float*)d_in[12];
    const float* skip_b  = (const float*)d_in[13];
    const float* gconv_w = (const float*)d_in[14];
    const float* gconv_b = (const float*)d_in[15];
    const float* bn_g    = (const float*)d_in[16];
    const float* bn_b    = (const float*)d_in[17];
    const float* bna_g   = (const float*)d_in[18];
    const float* bna_b   = (const float*)d_in[19];
    const float* end1_w  = (const float*)d_in[20];
    const float* end1_b  = (const float*)d_in[21];
    const float* end2_w  = (const float*)d_in[22];
    const float* end2_b  = (const float*)d_in[23];

    float* ws   = (float*)d_ws;
    float* tab  = ws + OFF_TAB;
    float* src  = ws + OFF_SRC;
    float* temp = ws + OFF_TEMP;
    float* Amat = ws + OFF_A;
    float* x    = ws + OFF_X;
    float* xs   = ws + OFF_XS;
    float* h1   = ws + OFF_H1;
    float* h2   = ws + OFF_H2;
    float* skip = ws + OFF_SKIP;

    k_tables<<<1, 64, 0, stream>>>(bn_g, bna_g, bna_b, starta_w, starta_b, tab);
    k_start<<<(NB*NCH*NL*NN)/256, 256, 0, stream>>>(inputs, start_w, start_b, x);
    k_srctemp<<<NB, 256, 0, stream>>>(p1, ind, pk, p2, p3, src, temp);
    k_A<<<dim3(16, 16, NB), 256, 0, stream>>>(src, temp, Amat);

    for (int i = 0; i < NLAY; i++) {
        k_fc<<<(NB*NL*NN)/256, 256, 0, stream>>>(x, xs, skip, fc1_w, fc2_w, skip_w, skip_b, i);
        k_gemm<<<dim3(16, 4, NB), 256, 0, stream>>>(xs, Amat, h1);
        k_gemm<<<dim3(16, 4, NB), 256, 0, stream>>>(h1, Amat, h2);
        k_epi<<<(NB*NL*NN)/256, 256, 0, stream>>>(x, xs, h1, h2, inputs, gconv_w, gconv_b, bn_b, tab, i);
    }
    k_end<<<dim3(16, NB), 256, 0, stream>>>(skip, end1_w, end1_b, end2_w, end2_b, (float*)d_out);
}

// Round 2
// 842.629 us; speedup vs baseline: 3.6701x; 3.6701x over previous
//
#include <hip/hip_runtime.h>
#include <math.h>

#define NB 16
#define NCH 16
#define NL 13
#define NN 1024
#define NT 12
#define NLAY 8
#define MROWS 208          // NCH*NL valid rows
#define MPAD 256           // padded plane rows

typedef _Float16 f16;
typedef __attribute__((ext_vector_type(8))) _Float16 f16x8;
typedef __attribute__((ext_vector_type(16))) float f32x16;

// ---------------- workspace layout (float offsets) ----------------
#define OFF_TAB   0
#define OFF_SRC   1024
#define OFF_TEMP  (OFF_SRC  + (size_t)NB*NN*32)
#define OFF_AH    (OFF_TEMP + (size_t)NB*NN*32)                 // A f16 [b][1024][1024]
#define OFF_XH    (OFF_AH   + (size_t)NB*NN*NN/2)               // xs hi f16 [b][256][1024]
#define OFF_XL    (OFF_XH   + (size_t)NB*MPAD*NN/2)
#define OFF_H1H   (OFF_XL   + (size_t)NB*MPAD*NN/2)
#define OFF_H1L   (OFF_H1H  + (size_t)NB*MPAD*NN/2)
#define OFF_H2    (OFF_H1L  + (size_t)NB*MPAD*NN/2)             // h2 f32 [b][256][1024]
#define OFF_X     (OFF_H2   + (size_t)NB*MPAD*NN)               // x f32 [b][208][1024]
#define OFF_SKIP  (OFF_X    + (size_t)NB*MROWS*NN)              // skip f32 [b][832][1024]
#define WS_FLOATS (OFF_SKIP + (size_t)NB*832*NN)

__device__ __forceinline__ void gload16(const void* g, void* l) {
    __builtin_amdgcn_global_load_lds(
        (const __attribute__((address_space(1))) unsigned int*)g,
        (__attribute__((address_space(3))) unsigned int*)l,
        16, 0, 0);
}

// ---------------- tables: bn scale + x_a affine recurrence ----------------
__global__ void k_tables(const float* __restrict__ bn_g,
                         const float* __restrict__ bna_g, const float* __restrict__ bna_b,
                         const float* __restrict__ sa_w, const float* __restrict__ sa_b,
                         float* __restrict__ tab) {
    int c = threadIdx.x;
    if (c >= 16) return;
    float inv = 1.0f / sqrtf(1.0f + 1e-5f);
    float A = sa_w[c], Bc = sa_b[c];
    for (int i = 0; i < NLAY; i++) {
        tab[i*16 + c]       = bn_g[i*16 + c] * inv;
        tab[128 + i*16 + c] = A;
        tab[256 + i*16 + c] = Bc;
        float ga = bna_g[i*16 + c] * inv;
        A  = 2.0f * ga * A;
        Bc = 2.0f * ga * Bc + bna_b[i*16 + c];
    }
}

// ---------------- start conv: x0[b, c*13+l, n] ----------------
__global__ __launch_bounds__(256) void k_start(const float* __restrict__ inp,
                        const float* __restrict__ sw, const float* __restrict__ sb,
                        float* __restrict__ x) {
    int idx = blockIdx.x * 256 + threadIdx.x;            // over B*C*L*N
    int n = idx & 1023;
    int rest = idx >> 10;
    int l = rest % 13; rest /= 13;
    int c = rest & 15;
    int b = rest >> 4;
    float u = (l == 0) ? 0.f : inp[((size_t)(b*2 + 0)*NN + n)*NT + (l - 1)];
    x[((size_t)b*MROWS + c*13 + l)*NN + n] = sw[c] * u + sb[c];
}

// ---------------- adp / src / temp (one block per batch) ----------------
__global__ __launch_bounds__(256) void k_srctemp(const float* __restrict__ p1, const int* __restrict__ ind,
                          const float* __restrict__ pk, const float* __restrict__ p2,
                          const float* __restrict__ p3,
                          float* __restrict__ src, float* __restrict__ temp) {
    __shared__ float te[32];
    __shared__ float adp[32][32];
    __shared__ float M[32][32];
    __shared__ float p3s[32][32];
    int b = blockIdx.x, t = threadIdx.x;
    if (t < 32) te[t] = p1[(size_t)ind[b]*32 + t];
    for (int i = t; i < 1024; i += 256) p3s[i >> 5][i & 31] = p3[i];
    __syncthreads();
    for (int i = t; i < 1024; i += 256) {
        int j = i >> 5, k = i & 31;
        float s = 0.f;
        for (int q = 0; q < 32; q++) s += te[q] * pk[q*1024 + j*32 + k];
        adp[j][k] = s;
    }
    __syncthreads();
    for (int i = t; i < 1024; i += 256) {
        int j = i >> 5, c = i & 31;
        float s = 0.f;
        for (int k = 0; k < 32; k++) s += adp[j][k] * p3s[c][k];
        M[j][c] = s;
    }
    __syncthreads();
    for (int n0 = 0; n0 < NN; n0 += 8) {
        int n = n0 + (t >> 5), k = t & 31;
        float rs = 0.f, rt = 0.f;
        for (int j = 0; j < 32; j++) {
            float pv = p2[n*32 + j];
            rs += pv * adp[j][k];
            rt += pv * M[j][k];
        }
        src [((size_t)b*NN + n)*32 + k] = rs;
        temp[((size_t)b*NN + n)*32 + k] = rt;
    }
}

// ---------------- A[b,n,m] = relu(tanh(x1[n,m]-x1[m,n])) -> f16 ----------------
__global__ __launch_bounds__(256) void k_A(const float* __restrict__ src, const float* __restrict__ temp,
                    f16* __restrict__ Amat) {
    int b = blockIdx.z, n0 = blockIdx.y*64, m0 = blockIdx.x*64;
    __shared__ float sn[64][33], tm[64][33], sm[64][33], tn[64][33];
    int t = threadIdx.x;
    const float* sb_ = src  + (size_t)b*NN*32;
    const float* tb_ = temp + (size_t)b*NN*32;
    for (int i = t; i < 64*32; i += 256) {
        int r = i >> 5, k = i & 31;
        sn[r][k] = sb_[(n0 + r)*32 + k];
        tm[r][k] = tb_[(m0 + r)*32 + k];
        sm[r][k] = sb_[(m0 + r)*32 + k];
        tn[r][k] = tb_[(n0 + r)*32 + k];
    }
    __syncthreads();
    int tr = (t >> 4) * 4, tc = (t & 15) * 4;
    float acc1[4][4] = {}, acc2[4][4] = {};
    for (int k = 0; k < 32; k++) {
        float a[4], bb[4], c2[4], d2[4];
        #pragma unroll
        for (int i = 0; i < 4; i++) { a[i]=sn[tr+i][k]; bb[i]=tm[tc+i][k]; c2[i]=sm[tc+i][k]; d2[i]=tn[tr+i][k]; }
        #pragma unroll
        for (int i = 0; i < 4; i++)
            #pragma unroll
            for (int j = 0; j < 4; j++) { acc1[i][j] += a[i]*bb[j]; acc2[i][j] += c2[j]*d2[i]; }
    }
    for (int i = 0; i < 4; i++)
        for (int j = 0; j < 4; j++) {
            float v = tanhf(acc1[i][j] - acc2[i][j]);
            Amat[((size_t)b*NN + n0 + tr + i)*NN + m0 + tc + j] = (f16)(v > 0.f ? v : 0.f);
        }
}

// ---------------- per-layer: fc1/relu/fc2/sigmoid + skip conv, write f16 planes ----------------
__global__ __launch_bounds__(256) void k_fc(const float* __restrict__ x, f16* __restrict__ xh,
                     f16* __restrict__ xl, float* __restrict__ skip,
                     const float* __restrict__ fc1, const float* __restrict__ fc2,
                     const float* __restrict__ skw, const float* __restrict__ skb, int layer) {
    __shared__ float W1[256], W2[256], W3[128], B3[8];
    int t = threadIdx.x;
    if (t < 256) { W1[t] = fc1[t]; W2[t] = fc2[t]; }
    if (t < 128) W3[t] = skw[layer*128 + t];
    if (t < 8)   B3[t] = skb[layer*8 + t];
    __syncthreads();
    int idx = blockIdx.x*256 + t;                         // over (b,l,n)
    int n = idx & 1023;
    int q = idx >> 10;
    int l = q % 13, b = q / 13;
    float v[16], t1[16], v2[16];
    #pragma unroll
    for (int c = 0; c < 16; c++) v[c] = x[((size_t)b*MROWS + c*13 + l)*NN + n];
    #pragma unroll
    for (int c = 0; c < 16; c++) {
        float s = 0.f;
        #pragma unroll
        for (int j = 0; j < 16; j++) s += W1[c*16 + j] * v[j];
        t1[c] = fmaxf(s, 0.f);
    }
    #pragma unroll
    for (int c = 0; c < 16; c++) {
        float s = 0.f;
        #pragma unroll
        for (int j = 0; j < 16; j++) s += W2[c*16 + j] * t1[j];
        float z = 2.f*s + v[c];
        v2[c] = 1.f / (1.f + expf(-z));
        size_t o = ((size_t)b*MPAD + c*13 + l)*NN + n;
        f16 hi = (f16)v2[c];
        xh[o] = hi;
        xl[o] = (f16)(v2[c] - (float)hi);
    }
    #pragma unroll
    for (int sc = 0; sc < 8; sc++) {
        float s = B3[sc];
        #pragma unroll
        for (int c = 0; c < 16; c++) s += W3[sc*16 + c] * v2[c];
        skip[((size_t)b*832 + (7 - layer)*104 + sc*13 + l)*NN + n] = s;
    }
}

// ---------------- MFMA GEMM: C[b][m][n] = sum_k (Xh+Xl)[m][k] * A[n][k] ----------------
// block: 64 M x 128 N, BK=64, 4 waves (wave-tile 32x64). f16 planes, swizzled LDS.
template<bool HOP1>
__global__ __launch_bounds__(256) void k_gmm(const f16* __restrict__ Xh, const f16* __restrict__ Xl,
                     const f16* __restrict__ Ag, float* __restrict__ Cf,
                     f16* __restrict__ Ch, f16* __restrict__ Cl) {
    __shared__ alignas(16) f16 As[128*64];     // 16 KB: [row 0..127][chunk-swizzled 64 f16]
    __shared__ alignas(16) f16 Xs[2*64*64];    // 16 KB: [plane][row 0..63][swizzled 64 f16]
    const int b  = blockIdx.z;
    const int n0 = blockIdx.x * 128;
    const int my = blockIdx.y;                 // m0 = my*64
    const int t = threadIdx.x;
    const int w = t >> 6, lane = t & 63;
    const char* Ab  = (const char*)(Ag + (size_t)b*NN*NN);
    const char* Xhb = (const char*)(Xh + (size_t)b*MPAD*NN);
    const char* Xlb = (const char*)(Xl + (size_t)b*MPAD*NN);

    const int wm = (w >> 1) * 32, wn = (w & 1) * 64;
    const int kh = lane >> 5;
    const int arow = wm + (lane & 31);
    const int brow0 = wn + (lane & 31);
    const int brow1 = brow0 + 32;
    const char* aP0 = (const char*)Xs + (size_t)arow*128;
    const char* aP1 = aP0 + 8192;
    const char* bP0 = (const char*)As + (size_t)brow0*128;
    const char* bP1 = (const char*)As + (size_t)brow1*128;
    const int swa = arow & 7, swb0 = brow0 & 7, swb1 = brow1 & 7;

    f32x16 acc0 = {}, acc1 = {};

    for (int k0 = 0; k0 < NN; k0 += 64) {
        // ---- stage A tile (128 rows x 64 f16) : 16 wave-loads ----
        const char* Abase = Ab + (size_t)n0*2048 + (size_t)k0*2;
        #pragma unroll
        for (int r = 0; r < 4; ++r) {
            int q = r*4 + w;
            int slot = q*64 + lane;
            int row = slot >> 3, ch = slot & 7;
            gload16(Abase + (size_t)row*2048 + ((ch ^ (row & 7)) << 4),
                    (char*)As + (size_t)q*1024);
        }
        // ---- stage X tiles (2 planes x 64 rows x 64 f16) : 16 wave-loads ----
        const char* Xb0 = Xhb + (size_t)(my*64)*2048 + (size_t)k0*2;
        const char* Xb1 = Xlb + (size_t)(my*64)*2048 + (size_t)k0*2;
        #pragma unroll
        for (int r = 0; r < 4; ++r) {
            int q = r*4 + w;                   // 0..15; plane = q>>3 (wave-uniform)
            int slot = q*64 + lane;
            int row = (slot >> 3) & 63, ch = slot & 7;
            const char* base = (q >> 3) ? Xb1 : Xb0;
            gload16(base + (size_t)row*2048 + ((ch ^ (row & 7)) << 4),
                    (char*)Xs + (size_t)q*1024);
        }
        __syncthreads();
        // ---- compute: 4 substeps of K=16 ----
        #pragma unroll
        for (int s = 0; s < 4; ++s) {
            int cn = s*2 + kh;
            f16x8 ah = *(const f16x8*)(aP0 + ((cn ^ swa) << 4));
            f16x8 al = *(const f16x8*)(aP1 + ((cn ^ swa) << 4));
            f16x8 b0 = *(const f16x8*)(bP0 + ((cn ^ swb0) << 4));
            f16x8 b1 = *(const f16x8*)(bP1 + ((cn ^ swb1) << 4));
            acc0 = __builtin_amdgcn_mfma_f32_32x32x16_f16(ah, b0, acc0, 0, 0, 0);
            acc1 = __builtin_amdgcn_mfma_f32_32x32x16_f16(ah, b1, acc1, 0, 0, 0);
            acc0 = __builtin_amdgcn_mfma_f32_32x32x16_f16(al, b0, acc0, 0, 0, 0);
            acc1 = __builtin_amdgcn_mfma_f32_32x32x16_f16(al, b1, acc1, 0, 0, 0);
        }
        __syncthreads();
    }

    // ---- epilogue: D row = (reg&3)+8*(reg>>2)+4*kh, col = lane&31 ----
    const int coll = lane & 31;
    #pragma unroll
    for (int reg = 0; reg < 16; ++reg) {
        int m = my*64 + wm + (reg & 3) + 8*(reg >> 2) + 4*kh;
        if (m < MROWS) {
            size_t o0 = ((size_t)b*MPAD + m)*NN + n0 + wn + coll;
            float v0 = acc0[reg], v1 = acc1[reg];
            if (HOP1) {
                f16 h0 = (f16)v0; Ch[o0]      = h0; Cl[o0]      = (f16)(v0 - (float)h0);
                f16 h1 = (f16)v1; Ch[o0 + 32] = h1; Cl[o0 + 32] = (f16)(v1 - (float)h1);
            } else {
                Cf[o0] = v0; Cf[o0 + 32] = v1;
            }
        }
    }
}

// ---------------- per-layer epilogue: gconv + x_a + residual + bn ----------------
__global__ __launch_bounds__(256) void k_epi(float* __restrict__ x,
                      const f16* __restrict__ xh, const f16* __restrict__ xl,
                      const f16* __restrict__ h1h, const f16* __restrict__ h1l,
                      const float* __restrict__ h2,
                      const float* __restrict__ inp, const float* __restrict__ gw,
                      const float* __restrict__ gb, const float* __restrict__ bnb,
                      const float* __restrict__ tab, int layer) {
    __shared__ float W[768], GB[16], BNB[16], BNS[16], AC[16], BC[16];
    int t = threadIdx.x;
    for (int i = t; i < 768; i += 256) W[i] = gw[layer*768 + i];
    if (t < 16) {
        GB[t]  = gb[layer*16 + t];
        BNB[t] = bnb[layer*16 + t];
        BNS[t] = tab[layer*16 + t];
        AC[t]  = tab[128 + layer*16 + t];
        BC[t]  = tab[256 + layer*16 + t];
    }
    __syncthreads();
    int idx = blockIdx.x*256 + t;
    int n = idx & 1023;
    int q = idx >> 10;
    int l = q % 13, b = q / 13;
    float u1 = (l == 0) ? 0.f : inp[((size_t)(b*2 + 1)*NN + n)*NT + (l - 1)];
    float vx[16], v1[16], v2[16], vo[16];
    #pragma unroll
    for (int c = 0; c < 16; c++) {
        size_t op = ((size_t)b*MPAD + c*13 + l)*NN + n;
        vx[c] = (float)xh[op] + (float)xl[op];
        v1[c] = (float)h1h[op] + (float)h1l[op];
        v2[c] = h2[op];
        vo[c] = x[((size_t)b*MROWS + c*13 + l)*NN + n];
    }
    #pragma unroll
    for (int o = 0; o < 16; o++) {
        float s = GB[o];
        #pragma unroll
        for (int c = 0; c < 16; c++) s += W[o*48 + c]      * vx[c];
        #pragma unroll
        for (int c = 0; c < 16; c++) s += W[o*48 + 16 + c] * v1[c];
        #pragma unroll
        for (int c = 0; c < 16; c++) s += W[o*48 + 32 + c] * v2[c];
        float xa = AC[o]*u1 + BC[o];
        x[((size_t)b*MROWS + o*13 + l)*NN + n] = BNS[o]*(s + xa + vo[o]) + BNB[o];
    }
}

// ---------------- end: out = end2·relu(end1·relu(skip)+b1)+b2 ----------------
__global__ __launch_bounds__(256) void k_end(const float* __restrict__ skip, const float* __restrict__ w1,
                      const float* __restrict__ b1, const float* __restrict__ w2,
                      const float* __restrict__ b2, float* __restrict__ outp) {
    __shared__ alignas(16) float Ss[64][68];
    __shared__ alignas(16) float Ws[64][68];
    int b = blockIdx.y, n0 = blockIdx.x * 64;
    int t = threadIdx.x, ty = t >> 4, tx = t & 15;
    float acc[4][4] = {};
    for (int k0 = 0; k0 < 832; k0 += 64) {
        for (int i = t; i < 4096; i += 256) {
            int r = i >> 6, c = i & 63;
            float sv = skip[((size_t)b*832 + k0 + r)*NN + n0 + c];
            Ss[r][c] = sv > 0.f ? sv : 0.f;
            Ws[c][r] = w1[(size_t)r*832 + k0 + c];
        }
        __syncthreads();
        #pragma unroll 8
        for (int k = 0; k < 64; k++) {
            float4 av = *(const float4*)&Ws[k][ty*4];
            float4 bv = *(const float4*)&Ss[k][tx*4];
            float a[4] = {av.x, av.y, av.z, av.w};
            float bb[4] = {bv.x, bv.y, bv.z, bv.w};
            #pragma unroll
            for (int i = 0; i < 4; i++)
                #pragma unroll
                for (int j = 0; j < 4; j++) acc[i][j] += a[i]*bb[j];
        }
        __syncthreads();
    }
    #pragma unroll
    for (int i = 0; i < 4; i++) {
        float bias = b1[ty*4 + i];
        #pragma unroll
        for (int j = 0; j < 4; j++) {
            float v = acc[i][j] + bias;
            Ss[ty*4 + i][tx*4 + j] = v > 0.f ? v : 0.f;
        }
    }
    __syncthreads();
    for (int idx = t; idx < 12*64; idx += 256) {
        int j = idx >> 6, n = idx & 63;
        float s = b2[j];
        for (int o = 0; o < 64; o++) s += w2[j*64 + o] * Ss[o][n];
        outp[((size_t)b*12 + j)*NN + n0 + n] = s;
    }
}

extern "C" void kernel_launch(void* const* d_in, const int* in_sizes, int n_in,
                              void* d_out, int out_size, void* d_ws, size_t ws_size,
                              hipStream_t stream) {
    (void)in_sizes; (void)n_in; (void)out_size;
    if (ws_size < WS_FLOATS * sizeof(float)) return;

    const float* inputs  = (const float*)d_in[0];
    const int*   ind     = (const int*)  d_in[1];
    const float* start_w = (const float*)d_in[2];
    const float* start_b = (const float*)d_in[3];
    const float* starta_w= (const float*)d_in[4];
    const float* starta_b= (const float*)d_in[5];
    const float* p1      = (const float*)d_in[6];
    const float* p2      = (const float*)d_in[7];
    const float* p3      = (const float*)d_in[8];
    const float* pk      = (const float*)d_in[9];
    const float* fc1_w   = (const float*)d_in[10];
    const float* fc2_w   = (const float*)d_in[11];
    const float* skip_w  = (const float*)d_in[12];
    const float* skip_b  = (const float*)d_in[13];
    const float* gconv_w = (const float*)d_in[14];
    const float* gconv_b = (const float*)d_in[15];
    const float* bn_g    = (const float*)d_in[16];
    const float* bn_b    = (const float*)d_in[17];
    const float* bna_g   = (const float*)d_in[18];
    const float* bna_b   = (const float*)d_in[19];
    const float* end1_w  = (const float*)d_in[20];
    const float* end1_b  = (const float*)d_in[21];
    const float* end2_w  = (const float*)d_in[22];
    const float* end2_b  = (const float*)d_in[23];

    float* ws   = (float*)d_ws;
    float* tab  = ws + OFF_TAB;
    float* src  = ws + OFF_SRC;
    float* temp = ws + OFF_TEMP;
    f16*   Ah   = (f16*)(ws + OFF_AH);
    f16*   xh   = (f16*)(ws + OFF_XH);
    f16*   xl   = (f16*)(ws + OFF_XL);
    f16*   h1h  = (f16*)(ws + OFF_H1H);
    f16*   h1l  = (f16*)(ws + OFF_H1L);
    float* h2   = ws + OFF_H2;
    float* x    = ws + OFF_X;
    float* skip = ws + OFF_SKIP;

    k_tables<<<1, 64, 0, stream>>>(bn_g, bna_g, bna_b, starta_w, starta_b, tab);
    k_start<<<(NB*NCH*NL*NN)/256, 256, 0, stream>>>(inputs, start_w, start_b, x);
    k_srctemp<<<NB, 256, 0, stream>>>(p1, ind, pk, p2, p3, src, temp);
    k_A<<<dim3(16, 16, NB), 256, 0, stream>>>(src, temp, Ah);

    for (int i = 0; i < NLAY; i++) {
        k_fc<<<(NB*NL*NN)/256, 256, 0, stream>>>(x, xh, xl, skip, fc1_w, fc2_w, skip_w, skip_b, i);
        k_gmm<true ><<<dim3(8, 4, NB), 256, 0, stream>>>(xh,  xl,  Ah, nullptr, h1h, h1l);
        k_gmm<false><<<dim3(8, 4, NB), 256, 0, stream>>>(h1h, h1l, Ah, h2, nullptr, nullptr);
        k_epi<<<(NB*NL*NN)/256, 256, 0, stream>>>(x, xh, xl, h1h, h1l, h2, inputs,
                                                  gconv_w, gconv_b, bn_b, tab, i);
    }
    k_end<<<dim3(16, NB), 256, 0, stream>>>(skip, end1_w, end1_b, end2_w, end2_b, (float*)d_out);
}

// Round 3
// 707.912 us; speedup vs baseline: 4.3685x; 1.1903x over previous
//
#include <hip/hip_runtime.h>
#include <math.h>

#define NB 16
#define NCH 16
#define NL 13
#define NN 1024
#define NT 12
#define NLAY 8
#define MROWS 208          // NCH*NL valid rows
#define MPAD 256           // padded plane rows

typedef _Float16 f16;
typedef __attribute__((ext_vector_type(8))) _Float16 f16x8;
typedef __attribute__((ext_vector_type(16))) float f32x16;

// ---------------- workspace layout (float offsets) ----------------
#define OFF_TAB   0
#define OFF_SRC   1024
#define OFF_TEMP  (OFF_SRC  + (size_t)NB*NN*32)
#define OFF_AH    (OFF_TEMP + (size_t)NB*NN*32)                 // A f16 [b][1024][1024]
#define OFF_XH    (OFF_AH   + (size_t)NB*NN*NN/2)               // xs hi f16 [b][256][1024]
#define OFF_XL    (OFF_XH   + (size_t)NB*MPAD*NN/2)
#define OFF_H1H   (OFF_XL   + (size_t)NB*MPAD*NN/2)
#define OFF_H1L   (OFF_H1H  + (size_t)NB*MPAD*NN/2)
#define OFF_H2    (OFF_H1L  + (size_t)NB*MPAD*NN/2)             // h2 f32 [b][256][1024]; reused as out1 partials
#define OFF_X     (OFF_H2   + (size_t)NB*MPAD*NN)               // x f32 [b][208][1024]
#define OFF_SKIP  (OFF_X    + (size_t)NB*MROWS*NN)              // skip f32 [b][832][1024]
#define WS_FLOATS (OFF_SKIP + (size_t)NB*832*NN)

__device__ __forceinline__ void gload16(const void* g, void* l) {
    __builtin_amdgcn_global_load_lds(
        (const __attribute__((address_space(1))) unsigned int*)g,
        (__attribute__((address_space(3))) unsigned int*)l,
        16, 0, 0);
}

__device__ __forceinline__ float fast_tanh(float x) {
    float e = __expf(2.0f * x);
    return 1.0f - 2.0f / (e + 1.0f);
}

// ---------------- tables: bn scale + x_a affine recurrence ----------------
__global__ void k_tables(const float* __restrict__ bn_g,
                         const float* __restrict__ bna_g, const float* __restrict__ bna_b,
                         const float* __restrict__ sa_w, const float* __restrict__ sa_b,
                         float* __restrict__ tab) {
    int c = threadIdx.x;
    if (c >= 16) return;
    float inv = 1.0f / sqrtf(1.0f + 1e-5f);
    float A = sa_w[c], Bc = sa_b[c];
    for (int i = 0; i < NLAY; i++) {
        tab[i*16 + c]       = bn_g[i*16 + c] * inv;
        tab[128 + i*16 + c] = A;
        tab[256 + i*16 + c] = Bc;
        float ga = bna_g[i*16 + c] * inv;
        A  = 2.0f * ga * A;
        Bc = 2.0f * ga * Bc + bna_b[i*16 + c];
    }
}

// ---------------- start conv + fc layer 0 ----------------
__global__ __launch_bounds__(256) void k_startfc(const float* __restrict__ inp,
                        const float* __restrict__ sw, const float* __restrict__ sb,
                        const float* __restrict__ fc1, const float* __restrict__ fc2,
                        const float* __restrict__ skw, const float* __restrict__ skb,
                        float* __restrict__ x, f16* __restrict__ xh, f16* __restrict__ xl,
                        float* __restrict__ skip) {
    __shared__ float W1[256], W2[256], W3[128], B3[8], SW[16], SB[16];
    int t = threadIdx.x;
    if (t < 256) { W1[t] = fc1[t]; W2[t] = fc2[t]; }
    if (t < 128) W3[t] = skw[t];             // layer 0
    if (t < 8)   B3[t] = skb[t];
    if (t < 16)  { SW[t] = sw[t]; SB[t] = sb[t]; }
    __syncthreads();
    int idx = blockIdx.x*256 + t;            // over (b,l,n)
    int n = idx & 1023;
    int q = idx >> 10;
    int l = q % 13, b = q / 13;
    float u = (l == 0) ? 0.f : inp[((size_t)(b*2 + 0)*NN + n)*NT + (l - 1)];
    float v[16], t1[16], v2[16];
    #pragma unroll
    for (int c = 0; c < 16; c++) {
        v[c] = SW[c]*u + SB[c];
        x[((size_t)b*MROWS + c*13 + l)*NN + n] = v[c];
    }
    #pragma unroll
    for (int c = 0; c < 16; c++) {
        float s = 0.f;
        #pragma unroll
        for (int j = 0; j < 16; j++) s += W1[c*16 + j] * v[j];
        t1[c] = fmaxf(s, 0.f);
    }
    #pragma unroll
    for (int c = 0; c < 16; c++) {
        float s = 0.f;
        #pragma unroll
        for (int j = 0; j < 16; j++) s += W2[c*16 + j] * t1[j];
        float z = 2.f*s + v[c];
        v2[c] = 1.f / (1.f + __expf(-z));
        size_t o = ((size_t)b*MPAD + c*13 + l)*NN + n;
        f16 hi = (f16)v2[c];
        xh[o] = hi;
        xl[o] = (f16)(v2[c] - (float)hi);
    }
    #pragma unroll
    for (int sc = 0; sc < 8; sc++) {
        float s = B3[sc];
        #pragma unroll
        for (int c = 0; c < 16; c++) s += W3[sc*16 + c] * v2[c];
        skip[((size_t)b*832 + 7*104 + sc*13 + l)*NN + n] = s;
    }
}

// ---------------- adp / src / temp (one block per batch) ----------------
__global__ __launch_bounds__(256) void k_srctemp(const float* __restrict__ p1, const int* __restrict__ ind,
                          const float* __restrict__ pk, const float* __restrict__ p2,
                          const float* __restrict__ p3,
                          float* __restrict__ src, float* __restrict__ temp) {
    __shared__ float te[32];
    __shared__ float adp[32][32];
    __shared__ float M[32][32];
    __shared__ float p3s[32][32];
    int b = blockIdx.x, t = threadIdx.x;
    if (t < 32) te[t] = p1[(size_t)ind[b]*32 + t];
    for (int i = t; i < 1024; i += 256) p3s[i >> 5][i & 31] = p3[i];
    __syncthreads();
    for (int i = t; i < 1024; i += 256) {
        int j = i >> 5, k = i & 31;
        float s = 0.f;
        for (int q = 0; q < 32; q++) s += te[q] * pk[q*1024 + j*32 + k];
        adp[j][k] = s;
    }
    __syncthreads();
    for (int i = t; i < 1024; i += 256) {
        int j = i >> 5, c = i & 31;
        float s = 0.f;
        for (int k = 0; k < 32; k++) s += adp[j][k] * p3s[c][k];
        M[j][c] = s;
    }
    __syncthreads();
    for (int n0 = 0; n0 < NN; n0 += 8) {
        int n = n0 + (t >> 5), k = t & 31;
        float rs = 0.f, rt = 0.f;
        for (int j = 0; j < 32; j++) {
            float pv = p2[n*32 + j];
            rs += pv * adp[j][k];
            rt += pv * M[j][k];
        }
        src [((size_t)b*NN + n)*32 + k] = rs;
        temp[((size_t)b*NN + n)*32 + k] = rt;
    }
}

// ---------------- A tiles: triangular grid, each block writes tile + mirror ----------------
__global__ __launch_bounds__(256) void k_A(const float* __restrict__ src, const float* __restrict__ temp,
                    f16* __restrict__ Amat) {
    int b = blockIdx.z;
    // triangular decode: tid -> (ti, tj), ti <= tj over 16 tiles
    int r = blockIdx.x, ti = 0;
    while (r >= 16 - ti) { r -= 16 - ti; ti++; }
    int tj = ti + r;
    int n0 = ti*64, m0 = tj*64;
    __shared__ float sn[64][33], tm[64][33], sm[64][33], tn[64][33];
    __shared__ f16 At[64][72];
    int t = threadIdx.x;
    const float* sb_ = src  + (size_t)b*NN*32;
    const float* tb_ = temp + (size_t)b*NN*32;
    for (int i = t; i < 64*32; i += 256) {
        int rr = i >> 5, k = i & 31;
        sn[rr][k] = sb_[(n0 + rr)*32 + k];
        tm[rr][k] = tb_[(m0 + rr)*32 + k];
        sm[rr][k] = sb_[(m0 + rr)*32 + k];
        tn[rr][k] = tb_[(n0 + rr)*32 + k];
    }
    __syncthreads();
    int tr = (t >> 4) * 4, tc = (t & 15) * 4;
    float acc1[4][4] = {}, acc2[4][4] = {};
    for (int k = 0; k < 32; k++) {
        float a[4], bb[4], c2[4], d2[4];
        #pragma unroll
        for (int i = 0; i < 4; i++) { a[i]=sn[tr+i][k]; bb[i]=tm[tc+i][k]; c2[i]=sm[tc+i][k]; d2[i]=tn[tr+i][k]; }
        #pragma unroll
        for (int i = 0; i < 4; i++)
            #pragma unroll
            for (int j = 0; j < 4; j++) { acc1[i][j] += a[i]*bb[j]; acc2[i][j] += c2[j]*d2[i]; }
    }
    // main tile: A[n0+row][m0+col] = relu(tanh(d)); mirror: A[m0+col][n0+row] = relu(-tanh(d))
    #pragma unroll
    for (int i = 0; i < 4; i++)
        #pragma unroll
        for (int j = 0; j < 4; j++) {
            float v = fast_tanh(acc1[i][j] - acc2[i][j]);
            Amat[((size_t)b*NN + n0 + tr + i)*NN + m0 + tc + j] = (f16)(v > 0.f ? v : 0.f);
            At[tc + j][tr + i] = (f16)(-v > 0.f ? -v : 0.f);
        }
    __syncthreads();
    // coalesced mirror write (duplicate-writes same values on diagonal blocks: benign)
    for (int i = t; i < 512; i += 256) {
        int rr = i >> 3, c8 = (i & 7) * 8;
        f16* dst = &Amat[((size_t)b*NN + m0 + rr)*NN + n0 + c8];
        #pragma unroll
        for (int k = 0; k < 8; k++) dst[k] = At[rr][c8 + k];
    }
}

// ---------------- MFMA GEMM: C[b][m][n] = sum_k (Xh+Xl)[m][k] * A[n][k] ----------------
// 1D grid, XCD-pinned: bid&7 = xcd, 2 batches per XCD. Tile 64M x 128N, BK=64.
template<bool HOP1>
__global__ __launch_bounds__(256) void k_gmm(const f16* __restrict__ Xh, const f16* __restrict__ Xl,
                     const f16* __restrict__ Ag, float* __restrict__ Cf,
                     f16* __restrict__ Ch, f16* __restrict__ Cl) {
    __shared__ alignas(16) f16 As[128*64];     // 16 KB
    __shared__ alignas(16) f16 Xs[2*64*64];    // 16 KB
    const int bid = blockIdx.x;                // 0..511
    const int xcd = bid & 7;
    const int j   = bid >> 3;                  // 0..63
    const int b   = xcd + ((j >> 5) << 3);     // batches {xcd, xcd+8}
    const int tile = j & 31;
    const int my  = tile >> 3;                 // 0..3
    const int n0  = (tile & 7) * 128;
    const int t = threadIdx.x;
    const int w = t >> 6, lane = t & 63;
    const char* Ab  = (const char*)(Ag + (size_t)b*NN*NN);
    const char* Xhb = (const char*)(Xh + (size_t)b*MPAD*NN);
    const char* Xlb = (const char*)(Xl + (size_t)b*MPAD*NN);

    const int wm = (w >> 1) * 32, wn = (w & 1) * 64;
    const int kh = lane >> 5;
    const int arow = wm + (lane & 31);
    const int brow0 = wn + (lane & 31);
    const int brow1 = brow0 + 32;
    const char* aP0 = (const char*)Xs + (size_t)arow*128;
    const char* aP1 = aP0 + 8192;
    const char* bP0 = (const char*)As + (size_t)brow0*128;
    const char* bP1 = (const char*)As + (size_t)brow1*128;
    const int swa = arow & 7, swb0 = brow0 & 7, swb1 = brow1 & 7;

    f32x16 acc0 = {}, acc1 = {};

    for (int k0 = 0; k0 < NN; k0 += 64) {
        const char* Abase = Ab + (size_t)n0*2048 + (size_t)k0*2;
        #pragma unroll
        for (int rr = 0; rr < 4; ++rr) {
            int q = rr*4 + w;
            int slot = q*64 + lane;
            int row = slot >> 3, ch = slot & 7;
            gload16(Abase + (size_t)row*2048 + ((ch ^ (row & 7)) << 4),
                    (char*)As + (size_t)q*1024);
        }
        const char* Xb0 = Xhb + (size_t)(my*64)*2048 + (size_t)k0*2;
        const char* Xb1 = Xlb + (size_t)(my*64)*2048 + (size_t)k0*2;
        #pragma unroll
        for (int rr = 0; rr < 4; ++rr) {
            int q = rr*4 + w;
            int slot = q*64 + lane;
            int row = (slot >> 3) & 63, ch = slot & 7;
            const char* base = (q >> 3) ? Xb1 : Xb0;
            gload16(base + (size_t)row*2048 + ((ch ^ (row & 7)) << 4),
                    (char*)Xs + (size_t)q*1024);
        }
        __syncthreads();
        #pragma unroll
        for (int s = 0; s < 4; ++s) {
            int cn = s*2 + kh;
            f16x8 ah = *(const f16x8*)(aP0 + ((cn ^ swa) << 4));
            f16x8 al = *(const f16x8*)(aP1 + ((cn ^ swa) << 4));
            f16x8 b0 = *(const f16x8*)(bP0 + ((cn ^ swb0) << 4));
            f16x8 b1 = *(const f16x8*)(bP1 + ((cn ^ swb1) << 4));
            acc0 = __builtin_amdgcn_mfma_f32_32x32x16_f16(ah, b0, acc0, 0, 0, 0);
            acc1 = __builtin_amdgcn_mfma_f32_32x32x16_f16(ah, b1, acc1, 0, 0, 0);
            acc0 = __builtin_amdgcn_mfma_f32_32x32x16_f16(al, b0, acc0, 0, 0, 0);
            acc1 = __builtin_amdgcn_mfma_f32_32x32x16_f16(al, b1, acc1, 0, 0, 0);
        }
        __syncthreads();
    }

    const int coll = lane & 31;
    #pragma unroll
    for (int reg = 0; reg < 16; ++reg) {
        int m = my*64 + wm + (reg & 3) + 8*(reg >> 2) + 4*kh;
        if (m < MROWS) {
            size_t o0 = ((size_t)b*MPAD + m)*NN + n0 + wn + coll;
            float v0 = acc0[reg], v1 = acc1[reg];
            if (HOP1) {
                f16 h0 = (f16)v0; Ch[o0]      = h0; Cl[o0]      = (f16)(v0 - (float)h0);
                f16 h1 = (f16)v1; Ch[o0 + 32] = h1; Cl[o0 + 32] = (f16)(v1 - (float)h1);
            } else {
                Cf[o0] = v0; Cf[o0 + 32] = v1;
            }
        }
    }
}

// ---------------- fused epilogue(layer) + fc(layer+1) ----------------
__global__ __launch_bounds__(256) void k_epifc(float* __restrict__ x,
                      f16* __restrict__ xh, f16* __restrict__ xl,
                      const f16* __restrict__ h1h, const f16* __restrict__ h1l,
                      const float* __restrict__ h2,
                      const float* __restrict__ inp, const float* __restrict__ gw,
                      const float* __restrict__ gb, const float* __restrict__ bnb,
                      const float* __restrict__ tab,
                      const float* __restrict__ fc1, const float* __restrict__ fc2,
                      const float* __restrict__ skw, const float* __restrict__ skb,
                      float* __restrict__ skip, int layer) {
    __shared__ float W[768], W1[256], W2[256], W3[128], B3[8];
    __shared__ float GB[16], BNBs[16], BNS[16], AC[16], BC[16];
    int t = threadIdx.x;
    for (int i = t; i < 768; i += 256) W[i] = gw[layer*768 + i];
    if (t < 256) { W1[t] = fc1[t]; W2[t] = fc2[t]; }
    int nl = layer + 1;
    if (t < 128) W3[t] = skw[nl*128 + t];
    if (t < 8)   B3[t] = skb[nl*8 + t];
    if (t < 16) {
        GB[t]   = gb[layer*16 + t];
        BNBs[t] = bnb[layer*16 + t];
        BNS[t]  = tab[layer*16 + t];
        AC[t]   = tab[128 + layer*16 + t];
        BC[t]   = tab[256 + layer*16 + t];
    }
    __syncthreads();
    int idx = blockIdx.x*256 + t;
    int n = idx & 1023;
    int q = idx >> 10;
    int l = q % 13, b = q / 13;
    float u1 = (l == 0) ? 0.f : inp[((size_t)(b*2 + 1)*NN + n)*NT + (l - 1)];
    float vx[16], v1[16], v2[16], xnew[16];
    #pragma unroll
    for (int c = 0; c < 16; c++) {
        size_t op = ((size_t)b*MPAD + c*13 + l)*NN + n;
        vx[c] = (float)xh[op] + (float)xl[op];
        v1[c] = (float)h1h[op] + (float)h1l[op];
        v2[c] = h2[op];
    }
    #pragma unroll
    for (int o = 0; o < 16; o++) {
        float s = GB[o];
        #pragma unroll
        for (int c = 0; c < 16; c++) s += W[o*48 + c]      * vx[c];
        #pragma unroll
        for (int c = 0; c < 16; c++) s += W[o*48 + 16 + c] * v1[c];
        #pragma unroll
        for (int c = 0; c < 16; c++) s += W[o*48 + 32 + c] * v2[c];
        float xa = AC[o]*u1 + BC[o];
        float vo = x[((size_t)b*MROWS + o*13 + l)*NN + n];
        xnew[o] = BNS[o]*(s + xa + vo) + BNBs[o];
    }
    if (layer < 6) {
        #pragma unroll
        for (int o = 0; o < 16; o++)
            x[((size_t)b*MROWS + o*13 + l)*NN + n] = xnew[o];
    }
    // fc of layer nl
    float t1[16], vs[16];
    #pragma unroll
    for (int c = 0; c < 16; c++) {
        float s = 0.f;
        #pragma unroll
        for (int j = 0; j < 16; j++) s += W1[c*16 + j] * xnew[j];
        t1[c] = fmaxf(s, 0.f);
    }
    #pragma unroll
    for (int c = 0; c < 16; c++) {
        float s = 0.f;
        #pragma unroll
        for (int j = 0; j < 16; j++) s += W2[c*16 + j] * t1[j];
        float z = 2.f*s + xnew[c];
        vs[c] = 1.f / (1.f + __expf(-z));
        if (layer < 6) {
            size_t o = ((size_t)b*MPAD + c*13 + l)*NN + n;
            f16 hi = (f16)vs[c];
            xh[o] = hi;
            xl[o] = (f16)(vs[c] - (float)hi);
        }
    }
    #pragma unroll
    for (int sc = 0; sc < 8; sc++) {
        float s = B3[sc];
        #pragma unroll
        for (int c = 0; c < 16; c++) s += W3[sc*16 + c] * vs[c];
        skip[((size_t)b*832 + (7 - nl)*104 + sc*13 + l)*NN + n] = s;
    }
}

// ---------------- end stage 1: split-K partial GEMM out1[ks] = W1 * relu(skip_chunk) ----------------
__global__ __launch_bounds__(256) void k_end1(const float* __restrict__ skip, const float* __restrict__ w1,
                       float* __restrict__ out1) {
    __shared__ alignas(16) float Ws[52][68];
    __shared__ alignas(16) float Ss[52][68];
    int n0 = blockIdx.x * 64, ks = blockIdx.y, b = blockIdx.z;
    int t = threadIdx.x, ty = t >> 4, tx = t & 15;
    float acc[4][4] = {};
    int kbase = ks * 208;
    for (int kk = 0; kk < 4; kk++) {
        int k0 = kbase + kk*52;
        for (int i = t; i < 52*64; i += 256) {
            int r = i >> 6, c = i & 63;
            float sv = skip[((size_t)b*832 + k0 + r)*NN + n0 + c];
            Ss[r][c] = sv > 0.f ? sv : 0.f;
            Ws[r][c] = w1[(size_t)c*832 + k0 + r];
        }
        __syncthreads();
        #pragma unroll 4
        for (int k = 0; k < 52; k++) {
            float4 av = *(const float4*)&Ws[k][ty*4];
            float4 bv = *(const float4*)&Ss[k][tx*4];
            float a[4] = {av.x, av.y, av.z, av.w};
            float bb[4] = {bv.x, bv.y, bv.z, bv.w};
            #pragma unroll
            for (int i = 0; i < 4; i++)
                #pragma unroll
                for (int jj = 0; jj < 4; jj++) acc[i][jj] += a[i]*bb[jj];
        }
        __syncthreads();
    }
    #pragma unroll
    for (int i = 0; i < 4; i++)
        #pragma unroll
        for (int jj = 0; jj < 4; jj++)
            out1[(((size_t)ks*NB + b)*64 + ty*4 + i)*NN + n0 + tx*4 + jj] = acc[i][jj];
}

// ---------------- end stage 2: combine partials, relu, 12x64 conv ----------------
__global__ __launch_bounds__(256) void k_end2(const float* __restrict__ out1, const float* __restrict__ b1,
                       const float* __restrict__ w2, const float* __restrict__ b2,
                       float* __restrict__ outp) {
    __shared__ float S[64][68];
    int n0 = blockIdx.x * 64, b = blockIdx.y;
    int t = threadIdx.x;
    for (int i = t; i < 4096; i += 256) {
        int o = i >> 6, n = i & 63;
        float s = b1[o];
        #pragma unroll
        for (int ks = 0; ks < 4; ks++)
            s += out1[(((size_t)ks*NB + b)*64 + o)*NN + n0 + n];
        S[o][n] = s > 0.f ? s : 0.f;
    }
    __syncthreads();
    for (int idx = t; idx < 12*64; idx += 256) {
        int jr = idx >> 6, n = idx & 63;
        float s = b2[jr];
        for (int o = 0; o < 64; o++) s += w2[jr*64 + o] * S[o][n];
        outp[((size_t)b*12 + jr)*NN + n0 + n] = s;
    }
}

extern "C" void kernel_launch(void* const* d_in, const int* in_sizes, int n_in,
                              void* d_out, int out_size, void* d_ws, size_t ws_size,
                              hipStream_t stream) {
    (void)in_sizes; (void)n_in; (void)out_size;
    if (ws_size < WS_FLOATS * sizeof(float)) return;

    const float* inputs  = (const float*)d_in[0];
    const int*   ind     = (const int*)  d_in[1];
    const float* start_w = (const float*)d_in[2];
    const float* start_b = (const float*)d_in[3];
    const float* starta_w= (const float*)d_in[4];
    const float* starta_b= (const float*)d_in[5];
    const float* p1      = (const float*)d_in[6];
    const float* p2      = (const float*)d_in[7];
    const float* p3      = (const float*)d_in[8];
    const float* pk      = (const float*)d_in[9];
    const float* fc1_w   = (const float*)d_in[10];
    const float* fc2_w   = (const float*)d_in[11];
    const float* skip_w  = (const float*)d_in[12];
    const float* skip_b  = (const float*)d_in[13];
    const float* gconv_w = (const float*)d_in[14];
    const float* gconv_b = (const float*)d_in[15];
    const float* bn_g    = (const float*)d_in[16];
    const float* bn_b    = (const float*)d_in[17];
    const float* bna_g   = (const float*)d_in[18];
    const float* bna_b   = (const float*)d_in[19];
    const float* end1_w  = (const float*)d_in[20];
    const float* end1_b  = (const float*)d_in[21];
    const float* end2_w  = (const float*)d_in[22];
    const float* end2_b  = (const float*)d_in[23];

    float* ws   = (float*)d_ws;
    float* tab  = ws + OFF_TAB;
    float* src  = ws + OFF_SRC;
    float* temp = ws + OFF_TEMP;
    f16*   Ah   = (f16*)(ws + OFF_AH);
    f16*   xh   = (f16*)(ws + OFF_XH);
    f16*   xl   = (f16*)(ws + OFF_XL);
    f16*   h1h  = (f16*)(ws + OFF_H1H);
    f16*   h1l  = (f16*)(ws + OFF_H1L);
    float* h2   = ws + OFF_H2;               // also reused as out1 partials after layer loop
    float* x    = ws + OFF_X;
    float* skip = ws + OFF_SKIP;

    k_tables<<<1, 64, 0, stream>>>(bn_g, bna_g, bna_b, starta_w, starta_b, tab);
    k_startfc<<<(NB*NL*NN)/256, 256, 0, stream>>>(inputs, start_w, start_b, fc1_w, fc2_w,
                                                  skip_w, skip_b, x, xh, xl, skip);
    k_srctemp<<<NB, 256, 0, stream>>>(p1, ind, pk, p2, p3, src, temp);
    k_A<<<dim3(136, 1, NB), 256, 0, stream>>>(src, temp, Ah);

    for (int i = 0; i < 7; i++) {            // layer 7's gemms/epilogue are dead code
        k_gmm<true ><<<512, 256, 0, stream>>>(xh,  xl,  Ah, nullptr, h1h, h1l);
        k_gmm<false><<<512, 256, 0, stream>>>(h1h, h1l, Ah, h2, nullptr, nullptr);
        k_epifc<<<(NB*NL*NN)/256, 256, 0, stream>>>(x, xh, xl, h1h, h1l, h2, inputs,
                                                    gconv_w, gconv_b, bn_b, tab,
                                                    fc1_w, fc2_w, skip_w, skip_b, skip, i);
    }
    k_end1<<<dim3(16, 4, NB), 256, 0, stream>>>(skip, end1_w, h2);
    k_end2<<<dim3(16, NB), 256, 0, stream>>>(h2, end1_b, end2_w, end2_b, (float*)d_out);
}

// Round 4
// 651.017 us; speedup vs baseline: 4.7502x; 1.0874x over previous
//
#include <hip/hip_runtime.h>
#include <math.h>

#define NB 16
#define NCH 16
#define NL 13
#define NN 1024
#define NT 12
#define NLAY 8
#define MROWS 208          // NCH*NL valid rows
#define MPAD 256           // padded plane rows

typedef _Float16 f16;
typedef __attribute__((ext_vector_type(8))) _Float16 f16x8;
typedef __attribute__((ext_vector_type(16))) float f32x16;

// ---------------- workspace layout (float offsets) ----------------
#define OFF_TAB   0
#define OFF_ADP   1024
#define OFF_M     (OFF_ADP  + (size_t)NB*1024)
#define OFF_SRC   (OFF_M    + (size_t)NB*1024)
#define OFF_TEMP  (OFF_SRC  + (size_t)NB*NN*32)
#define OFF_AH    (OFF_TEMP + (size_t)NB*NN*32)                 // A f16 [b][1024][1024]
#define OFF_XH    (OFF_AH   + (size_t)NB*NN*NN/2)               // xs hi f16 [b][256][1024]
#define OFF_XL    (OFF_XH   + (size_t)NB*MPAD*NN/2)
#define OFF_H1H   (OFF_XL   + (size_t)NB*MPAD*NN/2)
#define OFF_H1L   (OFF_H1H  + (size_t)NB*MPAD*NN/2)
#define OFF_H2    (OFF_H1L  + (size_t)NB*MPAD*NN/2)             // h2 f32; reused as out1 partials
#define OFF_X     (OFF_H2   + (size_t)NB*MPAD*NN)               // x f32 [b][208][1024]
#define OFF_SKIP  (OFF_X    + (size_t)NB*MROWS*NN)              // skip f32 [b][832][1024]
#define WS_FLOATS (OFF_SKIP + (size_t)NB*832*NN)

__device__ __forceinline__ void gload16(const void* g, void* l) {
    __builtin_amdgcn_global_load_lds(
        (const __attribute__((address_space(1))) unsigned int*)g,
        (__attribute__((address_space(3))) unsigned int*)l,
        16, 0, 0);
}

__device__ __forceinline__ float fast_tanh(float x) {
    float e = __expf(2.0f * x);
    return 1.0f - 2.0f / (e + 1.0f);
}

// ---------------- tables: bn scale + x_a affine recurrence ----------------
__global__ void k_tables(const float* __restrict__ bn_g,
                         const float* __restrict__ bna_g, const float* __restrict__ bna_b,
                         const float* __restrict__ sa_w, const float* __restrict__ sa_b,
                         float* __restrict__ tab) {
    int c = threadIdx.x;
    if (c >= 16) return;
    float inv = 1.0f / sqrtf(1.0f + 1e-5f);
    float A = sa_w[c], Bc = sa_b[c];
    for (int i = 0; i < NLAY; i++) {
        tab[i*16 + c]       = bn_g[i*16 + c] * inv;
        tab[128 + i*16 + c] = A;
        tab[256 + i*16 + c] = Bc;
        float ga = bna_g[i*16 + c] * inv;
        A  = 2.0f * ga * A;
        Bc = 2.0f * ga * Bc + bna_b[i*16 + c];
    }
}

// ---------------- start conv + fc layer 0 ----------------
__global__ __launch_bounds__(256) void k_startfc(const float* __restrict__ inp,
                        const float* __restrict__ sw, const float* __restrict__ sb,
                        const float* __restrict__ fc1, const float* __restrict__ fc2,
                        const float* __restrict__ skw, const float* __restrict__ skb,
                        float* __restrict__ x, f16* __restrict__ xh, f16* __restrict__ xl,
                        float* __restrict__ skip) {
    __shared__ float W1[256], W2[256], W3[128], B3[8], SW[16], SB[16];
    int t = threadIdx.x;
    if (t < 256) { W1[t] = fc1[t]; W2[t] = fc2[t]; }
    if (t < 128) W3[t] = skw[t];             // layer 0
    if (t < 8)   B3[t] = skb[t];
    if (t < 16)  { SW[t] = sw[t]; SB[t] = sb[t]; }
    __syncthreads();
    int idx = blockIdx.x*256 + t;            // over (b,l,n)
    int n = idx & 1023;
    int q = idx >> 10;
    int l = q % 13, b = q / 13;
    float u = (l == 0) ? 0.f : inp[((size_t)(b*2 + 0)*NN + n)*NT + (l - 1)];
    float v[16], t1[16], v2[16];
    #pragma unroll
    for (int c = 0; c < 16; c++) {
        v[c] = SW[c]*u + SB[c];
        x[((size_t)b*MROWS + c*13 + l)*NN + n] = v[c];
    }
    #pragma unroll
    for (int c = 0; c < 16; c++) {
        float s = 0.f;
        #pragma unroll
        for (int j = 0; j < 16; j++) s += W1[c*16 + j] * v[j];
        t1[c] = fmaxf(s, 0.f);
    }
    #pragma unroll
    for (int c = 0; c < 16; c++) {
        float s = 0.f;
        #pragma unroll
        for (int j = 0; j < 16; j++) s += W2[c*16 + j] * t1[j];
        float z = 2.f*s + v[c];
        v2[c] = 1.f / (1.f + __expf(-z));
        size_t o = ((size_t)b*MPAD + c*13 + l)*NN + n;
        f16 hi = (f16)v2[c];
        xh[o] = hi;
        xl[o] = (f16)(v2[c] - (float)hi);
    }
    #pragma unroll
    for (int sc = 0; sc < 8; sc++) {
        float s = B3[sc];
        #pragma unroll
        for (int c = 0; c < 16; c++) s += W3[sc*16 + c] * v2[c];
        skip[((size_t)b*832 + 7*104 + sc*13 + l)*NN + n] = s;
    }
}

// ---------------- adp / M (one block per batch, tiny) ----------------
__global__ __launch_bounds__(256) void k_adp(const float* __restrict__ p1, const int* __restrict__ ind,
                      const float* __restrict__ pk, const float* __restrict__ p3,
                      float* __restrict__ adpg, float* __restrict__ Mg) {
    __shared__ float te[32];
    __shared__ float adp[32][32];
    __shared__ float p3s[32][32];
    int b = blockIdx.x, t = threadIdx.x;
    if (t < 32) te[t] = p1[(size_t)ind[b]*32 + t];
    for (int i = t; i < 1024; i += 256) p3s[i >> 5][i & 31] = p3[i];
    __syncthreads();
    for (int i = t; i < 1024; i += 256) {
        float s = 0.f;
        for (int q = 0; q < 32; q++) s += te[q] * pk[q*1024 + i];
        adp[i >> 5][i & 31] = s;
        adpg[(size_t)b*1024 + i] = s;
    }
    __syncthreads();
    for (int i = t; i < 1024; i += 256) {
        int j = i >> 5, c = i & 31;
        float s = 0.f;
        for (int k = 0; k < 32; k++) s += adp[j][k] * p3s[c][k];
        Mg[(size_t)b*1024 + i] = s;
    }
}

// ---------------- src/temp: 8 blocks per batch, 128 n-rows each ----------------
__global__ __launch_bounds__(256) void k_st(const float* __restrict__ p2, const float* __restrict__ adpg,
                     const float* __restrict__ Mg,
                     float* __restrict__ src, float* __restrict__ temp) {
    __shared__ float adpS[32][32], MS[32][32], p2S[128][32];
    int b = blockIdx.y, n0 = blockIdx.x * 128, t = threadIdx.x;
    for (int i = t; i < 1024; i += 256) {
        adpS[i >> 5][i & 31] = adpg[(size_t)b*1024 + i];
        MS[i >> 5][i & 31]   = Mg[(size_t)b*1024 + i];
    }
    for (int i = t; i < 128*32; i += 256) p2S[i >> 5][i & 31] = p2[(size_t)(n0 + (i >> 5))*32 + (i & 31)];
    __syncthreads();
    int k = t & 31, g = t >> 5;
    for (int nn = g; nn < 128; nn += 8) {
        float rs = 0.f, rt = 0.f;
        #pragma unroll 8
        for (int j = 0; j < 32; j++) {
            float pv = p2S[nn][j];
            rs += pv * adpS[j][k];
            rt += pv * MS[j][k];
        }
        src [((size_t)b*NN + n0 + nn)*32 + k] = rs;
        temp[((size_t)b*NN + n0 + nn)*32 + k] = rt;
    }
}

// ---------------- A tiles: triangular grid, transposed-LDS float4 dots ----------------
__global__ __launch_bounds__(256) void k_A(const float* __restrict__ src, const float* __restrict__ temp,
                    f16* __restrict__ Amat) {
    int b = blockIdx.z;
    int r = blockIdx.x, ti = 0;
    while (r >= 16 - ti) { r -= 16 - ti; ti++; }
    int tj = ti + r;
    int n0 = ti*64, m0 = tj*64;
    __shared__ float snT[32][68], tmT[32][68], smT[32][68], tnT[32][68];
    __shared__ f16 At[64][72];
    int t = threadIdx.x;
    const float* sb_ = src  + (size_t)b*NN*32;
    const float* tb_ = temp + (size_t)b*NN*32;
    for (int i = t; i < 64*32; i += 256) {
        int rr = i >> 5, k = i & 31;
        snT[k][rr] = sb_[(n0 + rr)*32 + k];
        tmT[k][rr] = tb_[(m0 + rr)*32 + k];
        smT[k][rr] = sb_[(m0 + rr)*32 + k];
        tnT[k][rr] = tb_[(n0 + rr)*32 + k];
    }
    __syncthreads();
    int tr = (t >> 4) * 4, tc = (t & 15) * 4;
    float acc1[4][4] = {}, acc2[4][4] = {};
    #pragma unroll 4
    for (int k = 0; k < 32; k++) {
        float4 a  = *(const float4*)&snT[k][tr];
        float4 bb = *(const float4*)&tmT[k][tc];
        float4 c2 = *(const float4*)&smT[k][tc];
        float4 d2 = *(const float4*)&tnT[k][tr];
        float av[4] = {a.x, a.y, a.z, a.w};
        float bv[4] = {bb.x, bb.y, bb.z, bb.w};
        float cv[4] = {c2.x, c2.y, c2.z, c2.w};
        float dv[4] = {d2.x, d2.y, d2.z, d2.w};
        #pragma unroll
        for (int i = 0; i < 4; i++)
            #pragma unroll
            for (int jj = 0; jj < 4; jj++) { acc1[i][jj] += av[i]*bv[jj]; acc2[i][jj] += cv[jj]*dv[i]; }
    }
    #pragma unroll
    for (int i = 0; i < 4; i++)
        #pragma unroll
        for (int jj = 0; jj < 4; jj++) {
            float v = fast_tanh(acc1[i][jj] - acc2[i][jj]);
            Amat[((size_t)b*NN + n0 + tr + i)*NN + m0 + tc + jj] = (f16)(v > 0.f ? v : 0.f);
            At[tc + jj][tr + i] = (f16)(-v > 0.f ? -v : 0.f);
        }
    __syncthreads();
    for (int i = t; i < 512; i += 256) {
        int rr = i >> 3, c8 = (i & 7) * 8;
        f16* dst = &Amat[((size_t)b*NN + m0 + rr)*NN + n0 + c8];
        #pragma unroll
        for (int k = 0; k < 8; k++) dst[k] = At[rr][c8 + k];
    }
}

// ---------------- MFMA GEMM, 2-phase double-buffered pipeline ----------------
// C[b][m][n] = sum_k (Xh+Xl)[m][k] * A[n][k]; 1D XCD-pinned grid; tile 64M x 128N, BK=64.
template<bool HOP1>
__global__ __launch_bounds__(256) void k_gmm(const f16* __restrict__ Xh, const f16* __restrict__ Xl,
                     const f16* __restrict__ Ag, float* __restrict__ Cf,
                     f16* __restrict__ Ch, f16* __restrict__ Cl) {
    __shared__ alignas(16) f16 As[2][128*64];     // 2 x 16 KB
    __shared__ alignas(16) f16 Xs[2][2*64*64];    // 2 x 16 KB
    const int bid = blockIdx.x;                // 0..511
    const int xcd = bid & 7;
    const int j   = bid >> 3;
    const int b   = xcd + ((j >> 5) << 3);     // batches {xcd, xcd+8}
    const int tile = j & 31;
    const int my  = tile >> 3;
    const int n0  = (tile & 7) * 128;
    const int t = threadIdx.x;
    const int w = t >> 6, lane = t & 63;
    const char* Ab  = (const char*)(Ag + (size_t)b*NN*NN);
    const char* Xhb = (const char*)(Xh + (size_t)b*MPAD*NN);
    const char* Xlb = (const char*)(Xl + (size_t)b*MPAD*NN);

    // per-thread staging sources (k0=0), advance by 128 B per K-step
    const char* asrc[4];
    int adst[4];
    const char* xsrc[4];
    int xdst[4];
    {
        const char* Abase = Ab + (size_t)n0*2048;
        const char* Xb0 = Xhb + (size_t)(my*64)*2048;
        const char* Xb1 = Xlb + (size_t)(my*64)*2048;
        #pragma unroll
        for (int rr = 0; rr < 4; ++rr) {
            int q = rr*4 + w;
            int slot = q*64 + lane;
            int row = slot >> 3, ch = slot & 7;
            asrc[rr] = Abase + (size_t)row*2048 + ((ch ^ (row & 7)) << 4);
            adst[rr] = q*1024;
            int xrow = row & 63;
            xsrc[rr] = ((q >> 3) ? Xb1 : Xb0) + (size_t)xrow*2048 + ((ch ^ (xrow & 7)) << 4);
            xdst[rr] = q*1024;
        }
    }

    const int wm = (w >> 1) * 32, wn = (w & 1) * 64;
    const int kh = lane >> 5;
    const int arow = wm + (lane & 31);
    const int brow0 = wn + (lane & 31);
    const int brow1 = brow0 + 32;
    const int swa = arow & 7, swb0 = brow0 & 7, swb1 = brow1 & 7;

    f32x16 acc0 = {}, acc1 = {};

    auto stage = [&](int buf, int it) {
        size_t koff = (size_t)it * 128;
        #pragma unroll
        for (int rr = 0; rr < 4; ++rr)
            gload16(asrc[rr] + koff, (char*)As[buf] + adst[rr]);
        #pragma unroll
        for (int rr = 0; rr < 4; ++rr)
            gload16(xsrc[rr] + koff, (char*)Xs[buf] + xdst[rr]);
    };
    auto compute = [&](int buf) {
        const char* aP0 = (const char*)Xs[buf] + (size_t)arow*128;
        const char* aP1 = aP0 + 8192;
        const char* bP0 = (const char*)As[buf] + (size_t)brow0*128;
        const char* bP1 = (const char*)As[buf] + (size_t)brow1*128;
        #pragma unroll
        for (int s = 0; s < 4; ++s) {
            int cn = s*2 + kh;
            f16x8 ah = *(const f16x8*)(aP0 + ((cn ^ swa) << 4));
            f16x8 al = *(const f16x8*)(aP1 + ((cn ^ swa) << 4));
            f16x8 b0 = *(const f16x8*)(bP0 + ((cn ^ swb0) << 4));
            f16x8 b1 = *(const f16x8*)(bP1 + ((cn ^ swb1) << 4));
            acc0 = __builtin_amdgcn_mfma_f32_32x32x16_f16(ah, b0, acc0, 0, 0, 0);
            acc1 = __builtin_amdgcn_mfma_f32_32x32x16_f16(ah, b1, acc1, 0, 0, 0);
            acc0 = __builtin_amdgcn_mfma_f32_32x32x16_f16(al, b0, acc0, 0, 0, 0);
            acc1 = __builtin_amdgcn_mfma_f32_32x32x16_f16(al, b1, acc1, 0, 0, 0);
        }
    };

    stage(0, 0);
    int cur = 0;
    for (int it = 0; it < 15; ++it) {
        stage(cur ^ 1, it + 1);
        asm volatile("s_waitcnt vmcnt(8)" ::: "memory");   // prev buffer's 8 loads done
        __builtin_amdgcn_s_barrier();
        compute(cur);
        __builtin_amdgcn_s_barrier();                      // done reading cur before restage
        cur ^= 1;
    }
    asm volatile("s_waitcnt vmcnt(0)" ::: "memory");
    __builtin_amdgcn_s_barrier();
    compute(cur);

    const int coll = lane & 31;
    #pragma unroll
    for (int reg = 0; reg < 16; ++reg) {
        int m = my*64 + wm + (reg & 3) + 8*(reg >> 2) + 4*kh;
        if (m < MROWS) {
            size_t o0 = ((size_t)b*MPAD + m)*NN + n0 + wn + coll;
            float v0 = acc0[reg], v1 = acc1[reg];
            if (HOP1) {
                f16 h0 = (f16)v0; Ch[o0]      = h0; Cl[o0]      = (f16)(v0 - (float)h0);
                f16 h1 = (f16)v1; Ch[o0 + 32] = h1; Cl[o0 + 32] = (f16)(v1 - (float)h1);
            } else {
                Cf[o0] = v0; Cf[o0 + 32] = v1;
            }
        }
    }
}

// ---------------- fused epilogue(layer) + fc(layer+1) ----------------
__global__ __launch_bounds__(256) void k_epifc(float* __restrict__ x,
                      f16* __restrict__ xh, f16* __restrict__ xl,
                      const f16* __restrict__ h1h, const f16* __restrict__ h1l,
                      const float* __restrict__ h2,
                      const float* __restrict__ inp, const float* __restrict__ gw,
                      const float* __restrict__ gb, const float* __restrict__ bnb,
                      const float* __restrict__ tab,
                      const float* __restrict__ fc1, const float* __restrict__ fc2,
                      const float* __restrict__ skw, const float* __restrict__ skb,
                      float* __restrict__ skip, int layer) {
    __shared__ float W[768], W1[256], W2[256], W3[128], B3[8];
    __shared__ float GB[16], BNBs[16], BNS[16], AC[16], BC[16];
    int t = threadIdx.x;
    for (int i = t; i < 768; i += 256) W[i] = gw[layer*768 + i];
    if (t < 256) { W1[t] = fc1[t]; W2[t] = fc2[t]; }
    int nl = layer + 1;
    if (t < 128) W3[t] = skw[nl*128 + t];
    if (t < 8)   B3[t] = skb[nl*8 + t];
    if (t < 16) {
        GB[t]   = gb[layer*16 + t];
        BNBs[t] = bnb[layer*16 + t];
        BNS[t]  = tab[layer*16 + t];
        AC[t]   = tab[128 + layer*16 + t];
        BC[t]   = tab[256 + layer*16 + t];
    }
    __syncthreads();
    int idx = blockIdx.x*256 + t;
    int n = idx & 1023;
    int q = idx >> 10;
    int l = q % 13, b = q / 13;
    float u1 = (l == 0) ? 0.f : inp[((size_t)(b*2 + 1)*NN + n)*NT + (l - 1)];
    float vx[16], v1[16], v2[16], xnew[16];
    #pragma unroll
    for (int c = 0; c < 16; c++) {
        size_t op = ((size_t)b*MPAD + c*13 + l)*NN + n;
        vx[c] = (float)xh[op] + (float)xl[op];
        v1[c] = (float)h1h[op] + (float)h1l[op];
        v2[c] = h2[op];
    }
    #pragma unroll
    for (int o = 0; o < 16; o++) {
        float s = GB[o];
        #pragma unroll
        for (int c = 0; c < 16; c++) s += W[o*48 + c]      * vx[c];
        #pragma unroll
        for (int c = 0; c < 16; c++) s += W[o*48 + 16 + c] * v1[c];
        #pragma unroll
        for (int c = 0; c < 16; c++) s += W[o*48 + 32 + c] * v2[c];
        float xa = AC[o]*u1 + BC[o];
        float vo = x[((size_t)b*MROWS + o*13 + l)*NN + n];
        xnew[o] = BNS[o]*(s + xa + vo) + BNBs[o];
    }
    if (layer < 6) {
        #pragma unroll
        for (int o = 0; o < 16; o++)
            x[((size_t)b*MROWS + o*13 + l)*NN + n] = xnew[o];
    }
    float t1[16], vs[16];
    #pragma unroll
    for (int c = 0; c < 16; c++) {
        float s = 0.f;
        #pragma unroll
        for (int j = 0; j < 16; j++) s += W1[c*16 + j] * xnew[j];
        t1[c] = fmaxf(s, 0.f);
    }
    #pragma unroll
    for (int c = 0; c < 16; c++) {
        float s = 0.f;
        #pragma unroll
        for (int j = 0; j < 16; j++) s += W2[c*16 + j] * t1[j];
        float z = 2.f*s + xnew[c];
        vs[c] = 1.f / (1.f + __expf(-z));
        if (layer < 6) {
            size_t o = ((size_t)b*MPAD + c*13 + l)*NN + n;
            f16 hi = (f16)vs[c];
            xh[o] = hi;
            xl[o] = (f16)(vs[c] - (float)hi);
        }
    }
    #pragma unroll
    for (int sc = 0; sc < 8; sc++) {
        float s = B3[sc];
        #pragma unroll
        for (int c = 0; c < 16; c++) s += W3[sc*16 + c] * vs[c];
        skip[((size_t)b*832 + (7 - nl)*104 + sc*13 + l)*NN + n] = s;
    }
}

// ---------------- end stage 1: split-K partial GEMM ----------------
__global__ __launch_bounds__(256) void k_end1(const float* __restrict__ skip, const float* __restrict__ w1,
                       float* __restrict__ out1) {
    __shared__ alignas(16) float Ws[52][68];
    __shared__ alignas(16) float Ss[52][68];
    int n0 = blockIdx.x * 64, ks = blockIdx.y, b = blockIdx.z;
    int t = threadIdx.x, ty = t >> 4, tx = t & 15;
    float acc[4][4] = {};
    int kbase = ks * 208;
    for (int kk = 0; kk < 4; kk++) {
        int k0 = kbase + kk*52;
        for (int i = t; i < 52*64; i += 256) {
            int r = i >> 6, c = i & 63;
            float sv = skip[((size_t)b*832 + k0 + r)*NN + n0 + c];
            Ss[r][c] = sv > 0.f ? sv : 0.f;
            Ws[r][c] = w1[(size_t)c*832 + k0 + r];
        }
        __syncthreads();
        #pragma unroll 4
        for (int k = 0; k < 52; k++) {
            float4 av = *(const float4*)&Ws[k][ty*4];
            float4 bv = *(const float4*)&Ss[k][tx*4];
            float a[4] = {av.x, av.y, av.z, av.w};
            float bb[4] = {bv.x, bv.y, bv.z, bv.w};
            #pragma unroll
            for (int i = 0; i < 4; i++)
                #pragma unroll
                for (int jj = 0; jj < 4; jj++) acc[i][jj] += a[i]*bb[jj];
        }
        __syncthreads();
    }
    #pragma unroll
    for (int i = 0; i < 4; i++)
        #pragma unroll
        for (int jj = 0; jj < 4; jj++)
            out1[(((size_t)ks*NB + b)*64 + ty*4 + i)*NN + n0 + tx*4 + jj] = acc[i][jj];
}

// ---------------- end stage 2: combine partials, relu, 12x64 conv ----------------
__global__ __launch_bounds__(256) void k_end2(const float* __restrict__ out1, const float* __restrict__ b1,
                       const float* __restrict__ w2, const float* __restrict__ b2,
                       float* __restrict__ outp) {
    __shared__ float S[64][68];
    int n0 = blockIdx.x * 64, b = blockIdx.y;
    int t = threadIdx.x;
    for (int i = t; i < 4096; i += 256) {
        int o = i >> 6, n = i & 63;
        float s = b1[o];
        #pragma unroll
        for (int ks = 0; ks < 4; ks++)
            s += out1[(((size_t)ks*NB + b)*64 + o)*NN + n0 + n];
        S[o][n] = s > 0.f ? s : 0.f;
    }
    __syncthreads();
    for (int idx = t; idx < 12*64; idx += 256) {
        int jr = idx >> 6, n = idx & 63;
        float s = b2[jr];
        for (int o = 0; o < 64; o++) s += w2[jr*64 + o] * S[o][n];
        outp[((size_t)b*12 + jr)*NN + n0 + n] = s;
    }
}

extern "C" void kernel_launch(void* const* d_in, const int* in_sizes, int n_in,
                              void* d_out, int out_size, void* d_ws, size_t ws_size,
                              hipStream_t stream) {
    (void)in_sizes; (void)n_in; (void)out_size;
    if (ws_size < WS_FLOATS * sizeof(float)) return;

    const float* inputs  = (const float*)d_in[0];
    const int*   ind     = (const int*)  d_in[1];
    const float* start_w = (const float*)d_in[2];
    const float* start_b = (const float*)d_in[3];
    const float* starta_w= (const float*)d_in[4];
    const float* starta_b= (const float*)d_in[5];
    const float* p1      = (const float*)d_in[6];
    const float* p2      = (const float*)d_in[7];
    const float* p3      = (const float*)d_in[8];
    const float* pk      = (const float*)d_in[9];
    const float* fc1_w   = (const float*)d_in[10];
    const float* fc2_w   = (const float*)d_in[11];
    const float* skip_w  = (const float*)d_in[12];
    const float* skip_b  = (const float*)d_in[13];
    const float* gconv_w = (const float*)d_in[14];
    const float* gconv_b = (const float*)d_in[15];
    const float* bn_g    = (const float*)d_in[16];
    const float* bn_b    = (const float*)d_in[17];
    const float* bna_g   = (const float*)d_in[18];
    const float* bna_b   = (const float*)d_in[19];
    const float* end1_w  = (const float*)d_in[20];
    const float* end1_b  = (const float*)d_in[21];
    const float* end2_w  = (const float*)d_in[22];
    const float* end2_b  = (const float*)d_in[23];

    float* ws   = (float*)d_ws;
    float* tab  = ws + OFF_TAB;
    float* adpg = ws + OFF_ADP;
    float* Mg   = ws + OFF_M;
    float* src  = ws + OFF_SRC;
    float* temp = ws + OFF_TEMP;
    f16*   Ah   = (f16*)(ws + OFF_AH);
    f16*   xh   = (f16*)(ws + OFF_XH);
    f16*   xl   = (f16*)(ws + OFF_XL);
    f16*   h1h  = (f16*)(ws + OFF_H1H);
    f16*   h1l  = (f16*)(ws + OFF_H1L);
    float* h2   = ws + OFF_H2;               // reused as out1 partials after layer loop
    float* x    = ws + OFF_X;
    float* skip = ws + OFF_SKIP;

    k_tables<<<1, 64, 0, stream>>>(bn_g, bna_g, bna_b, starta_w, starta_b, tab);
    k_startfc<<<(NB*NL*NN)/256, 256, 0, stream>>>(inputs, start_w, start_b, fc1_w, fc2_w,
                                                  skip_w, skip_b, x, xh, xl, skip);
    k_adp<<<NB, 256, 0, stream>>>(p1, ind, pk, p3, adpg, Mg);
    k_st<<<dim3(8, NB), 256, 0, stream>>>(p2, adpg, Mg, src, temp);
    k_A<<<dim3(136, 1, NB), 256, 0, stream>>>(src, temp, Ah);

    for (int i = 0; i < 7; i++) {            // layer 7's gemms/epilogue are dead code
        k_gmm<true ><<<512, 256, 0, stream>>>(xh,  xl,  Ah, nullptr, h1h, h1l);
        k_gmm<false><<<512, 256, 0, stream>>>(h1h, h1l, Ah, h2, nullptr, nullptr);
        k_epifc<<<(NB*NL*NN)/256, 256, 0, stream>>>(x, xh, xl, h1h, h1l, h2, inputs,
                                                    gconv_w, gconv_b, bn_b, tab,
                                                    fc1_w, fc2_w, skip_w, skip_b, skip, i);
    }
    k_end1<<<dim3(16, 4, NB), 256, 0, stream>>>(skip, end1_w, h2);
    k_end2<<<dim3(16, NB), 256, 0, stream>>>(h2, end1_b, end2_w, end2_b, (float*)d_out);
}